// Round 19
// baseline (127.911 us; speedup 1.0000x reference)
//
#include <hip/hip_runtime.h>

typedef unsigned short u16;
typedef unsigned int u32;
typedef __attribute__((ext_vector_type(4))) float f32x4;
typedef __attribute__((ext_vector_type(8))) __bf16 bf16x8;
typedef __attribute__((ext_vector_type(8))) unsigned short u16x8;

#define MAXP_ 4096
#define TOTROWS 16384   // B*HQ*S = 2*16*512
#define NCHUNK 8
#define NCALLOC 8
#define CHUNKP 256

__device__ __forceinline__ u16 f2bf(float f) {
    union { float f; u32 u; } x; x.f = f;
    u32 r = x.u + 0x7FFFu + ((x.u >> 16) & 1u);
    return (u16)(r >> 16);
}
__device__ __forceinline__ float bf2f(u16 u) {
    union { u32 u; float f; } x; x.u = ((u32)u) << 16; return x.f;
}
// RNE bf16 pair pack
__device__ __forceinline__ u32 packbf(float lo, float hi) {
    return (u32)f2bf(lo) | ((u32)f2bf(hi) << 16);
}
__device__ __forceinline__ u32 bperm(int addr, u32 src) {
    return (u32)__builtin_amdgcn_ds_bpermute(addr, (int)src);
}

#define GLOAD16(g, l) __builtin_amdgcn_global_load_lds( \
    (const __attribute__((address_space(1))) void*)(g), \
    (__attribute__((address_space(3))) void*)(l), 16, 0, 0)

// ---------------- mega-prep: cvt + Wq/Wk/Wv/Wo transpose + K/V bf16 caches ----------------
// grid audit (R14 lesson): [0,1024) cvt | [1024,2048) Wq | [2048,2304) Wk | [2304,2560) Wv |
//                          [2560,3584) K/V caches (16 bkh x 64 p-tiles) | [3584,4608) Wo. grid=4608.
__global__ __launch_bounds__(256) void prep(const float* __restrict__ hidden,
        const float* __restrict__ Wq, const float* __restrict__ Wk, const float* __restrict__ Wv,
        const float* __restrict__ Wo, const float* __restrict__ past,
        u16* __restrict__ hb, u16* __restrict__ Wqkvt, u16* __restrict__ Wot,
        u16* __restrict__ Kc, u16* __restrict__ Vtc,
        const int* __restrict__ startp, const int* __restrict__ ctxp) {
    __shared__ __align__(16) u16 T[128][72];
    const int bid = blockIdx.x;
    const int t = threadIdx.x;
    if (bid < 1024) {   // cvt: 262144 groups of 8
        int i = bid * 256 + t;
        const float* s = hidden + (long)i * 8;
        f32x4 a = *(const f32x4*)s;
        f32x4 b = *(const f32x4*)(s + 4);
        u16x8 o;
#pragma unroll
        for (int j = 0; j < 4; ++j) { o[j] = f2bf(a[j]); o[4 + j] = f2bf(b[j]); }
        *(u16x8*)&hb[(long)i * 8] = o;
        return;
    }
    if (bid >= 2560 && bid < 3584) {   // bf16 K / V^T caches from past
        const int b2 = bid - 2560;
        const int bkh = b2 >> 6;            // (b*2+kv)*4+h
        const int p0 = (b2 & 63) * 64;
        const int b = bkh >> 3, kv = (bkh >> 2) & 1, h = bkh & 3;
        int klim = startp[0] + 512;
        int cx = ctxp[b];
        if (klim > cx) klim = cx;
        if (p0 >= klim) return;             // block-uniform
        const int p = t >> 2, d0 = (t & 3) * 32;
        const float* src = past + ((long)bkh * MAXP_ + p0 + p) * 128 + d0;
        f32x4 v[8];
#pragma unroll
        for (int j = 0; j < 8; ++j) v[j] = *(const f32x4*)(src + j * 4);
        if (kv == 0) {
            u16* kd = Kc + ((long)(b * 4 + h) * MAXP_ + p0 + p) * 128 + d0;
#pragma unroll
            for (int j2 = 0; j2 < 4; ++j2) {
                u16x8 o;
#pragma unroll
                for (int e = 0; e < 4; ++e) { o[e] = f2bf(v[j2 * 2][e]); o[4 + e] = f2bf(v[j2 * 2 + 1][e]); }
                *(u16x8*)&kd[j2 * 8] = o;
            }
        } else {
#pragma unroll
            for (int j = 0; j < 8; ++j)
#pragma unroll
                for (int e = 0; e < 4; ++e)
                    T[d0 + j * 4 + e][p] = f2bf(v[j][e]);
            __syncthreads();
            int d = t >> 1, pc = (t & 1) * 32;
            u16* vd = Vtc + ((long)(b * 4 + h) * 128 + d) * MAXP_ + p0 + pc;
#pragma unroll
            for (int j = 0; j < 4; ++j)
                *(u16x8*)&vd[j * 8] = *(const u16x8*)&T[d][pc + j * 8];
        }
        return;
    }
    // weight transpose branches (use rows [0,64) of T)
    const float* W; u16* Wdst; int N_w, n_off, n0, k0;
    if (bid < 2048)      { int b2 = bid - 1024; W = Wq; Wdst = Wqkvt; N_w = 2048; n_off = 0;    n0 = (b2 & 31) * 64; k0 = (b2 >> 5) * 64; }
    else if (bid < 2304) { int b2 = bid - 2048; W = Wk; Wdst = Wqkvt; N_w = 512;  n_off = 2048; n0 = (b2 & 7) * 64;  k0 = (b2 >> 3) * 64; }
    else if (bid < 2560) { int b2 = bid - 2304; W = Wv; Wdst = Wqkvt; N_w = 512;  n_off = 2560; n0 = (b2 & 7) * 64;  k0 = (b2 >> 3) * 64; }
    else                 { int b2 = bid - 3584; W = Wo; Wdst = Wot;   N_w = 2048; n_off = 0;    n0 = (b2 & 31) * 64; k0 = (b2 >> 5) * 64; }
    {
        int r = t >> 2, c4 = (t & 3) * 16;
        const float* src = W + (long)(k0 + r) * N_w + n0 + c4;
        f32x4 a0 = *(const f32x4*)src, a1 = *(const f32x4*)(src + 4);
        f32x4 a2 = *(const f32x4*)(src + 8), a3 = *(const f32x4*)(src + 12);
        u16x8 p0, p1;
#pragma unroll
        for (int j = 0; j < 4; ++j) {
            p0[j] = f2bf(a0[j]); p0[4 + j] = f2bf(a1[j]);
            p1[j] = f2bf(a2[j]); p1[4 + j] = f2bf(a3[j]);
        }
        *(u16x8*)&T[r][c4] = p0;
        *(u16x8*)&T[r][c4 + 8] = p1;
    }
    __syncthreads();
    {
        int n = t >> 2, k4 = (t & 3) * 16;
        u16x8 q0, q1;
#pragma unroll
        for (int j = 0; j < 8; ++j) { q0[j] = T[k4 + j][n]; q1[j] = T[k4 + 8 + j][n]; }
        u16* dst = Wdst + (long)(n_off + n0 + n) * 2048 + k0 + k4;
        *(u16x8*)dst = q0;
        *(u16x8*)(dst + 8) = q1;
    }
}

// ---------------- bf16 GEMM, A[M][K] @ Bt[N][K]^T -> C[M][N] f32 ----------------
// 64x64 tile, BK=64, dbuf gload_lds + counted vmcnt. 1D grid with XCD-pinned n-ranges (T1).
__global__ __launch_bounds__(256) void gemm64(const u16* __restrict__ A, const u16* __restrict__ Bt,
                                              float* __restrict__ C, int M, int N, int K) {
    __shared__ __align__(16) u16 As0[4096], Bs0[4096], As1[4096], Bs1[4096];
    const int tid = threadIdx.x, lane = tid & 63, w = tid >> 6;
    const int wm = w >> 1, wn = w & 1;
    const int l15 = lane & 15, g = lane >> 4;
    const int ntile = N >> 6, npx = ntile >> 3;
    const int xcd = blockIdx.x & 7, j_ = blockIdx.x >> 3;
    const int m0 = (j_ / npx) * 64, n0 = (xcd * npx + j_ % npx) * 64;
    f32x4 acc[2][2] = {};

    const int lrow = lane >> 3;
    const int sch = (lane & 7) ^ lrow;
    const int c0 = w, c1 = w + 4;
    const u16* ga0 = A + (long)(m0 + c0 * 8 + lrow) * K + sch * 8;
    const u16* ga1 = A + (long)(m0 + c1 * 8 + lrow) * K + sch * 8;
    const u16* gb0 = Bt + (long)(n0 + c0 * 8 + lrow) * K + sch * 8;
    const u16* gb1 = Bt + (long)(n0 + c1 * 8 + lrow) * K + sch * 8;
    const int ra = wm * 32, rb = wn * 32;
    const int h7 = l15 & 7;

#define STAGE_T(koff, AS_, BS_) do { \
        GLOAD16(ga0 + (koff), &AS_[c0 * 512]); \
        GLOAD16(ga1 + (koff), &AS_[c1 * 512]); \
        GLOAD16(gb0 + (koff), &BS_[c0 * 512]); \
        GLOAD16(gb1 + (koff), &BS_[c1 * 512]); \
    } while (0)

    auto compute = [&](const u16* as_, const u16* bs_) {
        bf16x8 af[2][2], bfr[2][2];
#pragma unroll
        for (int i = 0; i < 2; ++i) {
            int rr = ra + i * 16 + l15;
#pragma unroll
            for (int kk = 0; kk < 2; ++kk)
                af[i][kk] = *(const bf16x8*)&as_[rr * 64 + (((kk * 4 + g) ^ h7) * 8)];
        }
#pragma unroll
        for (int j2 = 0; j2 < 2; ++j2) {
            int rr = rb + j2 * 16 + l15;
#pragma unroll
            for (int kk = 0; kk < 2; ++kk)
                bfr[j2][kk] = *(const bf16x8*)&bs_[rr * 64 + (((kk * 4 + g) ^ h7) * 8)];
        }
#pragma unroll
        for (int i = 0; i < 2; ++i)
#pragma unroll
            for (int j2 = 0; j2 < 2; ++j2) {
                acc[i][j2] = __builtin_amdgcn_mfma_f32_16x16x32_bf16(af[i][0], bfr[j2][0], acc[i][j2], 0, 0, 0);
                acc[i][j2] = __builtin_amdgcn_mfma_f32_16x16x32_bf16(af[i][1], bfr[j2][1], acc[i][j2], 0, 0, 0);
            }
    };

    STAGE_T(0, As0, Bs0);
    for (int k0 = 0; k0 < K; k0 += 128) {
        STAGE_T(k0 + 64, As1, Bs1);
        asm volatile("s_waitcnt vmcnt(4)" ::: "memory");
        __builtin_amdgcn_s_barrier();
        __builtin_amdgcn_sched_barrier(0);
        compute(As0, Bs0);
        __builtin_amdgcn_s_barrier();
        if (k0 + 128 < K) {
            STAGE_T(k0 + 128, As0, Bs0);
            asm volatile("s_waitcnt vmcnt(4)" ::: "memory");
        } else {
            asm volatile("s_waitcnt vmcnt(0)" ::: "memory");
        }
        __builtin_amdgcn_s_barrier();
        __builtin_amdgcn_sched_barrier(0);
        compute(As1, Bs1);
        __builtin_amdgcn_s_barrier();
    }
#undef STAGE_T

#pragma unroll
    for (int i = 0; i < 2; ++i)
#pragma unroll
        for (int j2 = 0; j2 < 2; ++j2)
#pragma unroll
            for (int r = 0; r < 4; ++r)
                C[(long)(m0 + ra + i * 16 + g * 4 + r) * N + n0 + rb + j2 * 16 + l15] = acc[i][j2][r];
}

// ---------------- fused RMS norm + RoPE + cache scatter + new-V transpose ----------------
__global__ __launch_bounds__(256) void normrope_v(const float* __restrict__ QKVf,
        const float* __restrict__ rope,
        const float* __restrict__ qw, const float* __restrict__ kw,
        const int* __restrict__ startp, float* __restrict__ present,
        u16* __restrict__ Qn, u16* __restrict__ Kc, u16* __restrict__ Vtc) {
    const int bid = blockIdx.x;
    const int start = startp[0];
    if (bid < 6144) {
        const int wid = bid * 4 + (threadIdx.x >> 6);
        const int lane = threadIdx.x & 63;
        if (wid < 16384) { // Q: 1024 rows x 16 heads
            int row = wid >> 4, h = wid & 15;
            int b = row >> 9, s = row & 511;
            const float* src = QKVf + (long)row * 3072 + h * 128;
            float x1 = src[lane], x2 = src[64 + lane];
            float v = x1 * x1 + x2 * x2;
#pragma unroll
            for (int off = 32; off; off >>= 1) v += __shfl_xor(v, off, 64);
            float sc = rsqrtf(v * (1.0f / 128.0f) + 1e-6f);
            float y1 = x1 * sc * qw[lane], y2 = x2 * sc * qw[64 + lane];
            float c = rope[(long)row * 128 + lane], sn = rope[(long)row * 128 + 64 + lane];
            u16* dst = Qn + (((long)(b * 16 + h) * 512 + s) * 128);
            dst[lane] = f2bf(y1 * c - y2 * sn);
            dst[64 + lane] = f2bf(y2 * c + y1 * sn);
        } else if (wid < 20480) { // K: 1024 rows x 4 heads
            int j = wid - 16384;
            int row = j >> 2, h = j & 3;
            int b = row >> 9, s = row & 511;
            const float* src = QKVf + (long)row * 3072 + 2048 + h * 128;
            float x1 = src[lane], x2 = src[64 + lane];
            float v = x1 * x1 + x2 * x2;
#pragma unroll
            for (int off = 32; off; off >>= 1) v += __shfl_xor(v, off, 64);
            float sc = rsqrtf(v * (1.0f / 128.0f) + 1e-6f);
            float y1 = x1 * sc * kw[lane], y2 = x2 * sc * kw[64 + lane];
            float c = rope[(long)row * 128 + lane], sn = rope[(long)row * 128 + 64 + lane];
            float k1 = y1 * c - y2 * sn, k2 = y2 * c + y1 * sn;
            float* dst = present + (((long)(b * 2 + 0) * 4 + h) * MAXP_ + (start + s)) * 128;
            dst[lane] = k1; dst[64 + lane] = k2;
            u16* kc = Kc + (((long)(b * 4 + h)) * MAXP_ + start + s) * 128;
            kc[lane] = f2bf(k1); kc[64 + lane] = f2bf(k2);
        } else if (wid < 24576) { // V: present copy only
            int j = wid - 20480;
            int row = j >> 2, h = j & 3;
            int b = row >> 9, s = row & 511;
            const float* src = QKVf + (long)row * 3072 + 2560 + h * 128;
            float* dst = present + (((long)(b * 2 + 1) * 4 + h) * MAXP_ + (start + s)) * 128;
            dst[lane] = src[lane];
            dst[64 + lane] = src[64 + lane];
        }
        return;
    }
    // vtrans: new V -> Vtc bf16 [d][p]
    __shared__ __align__(16) u16 T[128][72];
    const int t = threadIdx.x;
    const int b2 = bid - 6144;
    const int s0 = (b2 & 7) * 64;
    const int bh = b2 >> 3, b = bh >> 2, h = bh & 3;
    const int sr = t >> 2, d0 = (t & 3) * 32;
    const float* src = QKVf + (long)(b * 512 + s0 + sr) * 3072 + 2560 + h * 128 + d0;
#pragma unroll
    for (int j = 0; j < 8; ++j) {
        f32x4 v = *(const f32x4*)(src + j * 4);
#pragma unroll
        for (int e = 0; e < 4; ++e) T[d0 + j * 4 + e][sr] = f2bf(v[e]);
    }
    __syncthreads();
    const int d = t >> 1, pc = (t & 1) * 32;
    u16* dst = Vtc + ((long)(b * 4 + h) * 128 + d) * MAXP_ + start + s0 + pc;
#pragma unroll
    for (int k = 0; k < 32; ++k) dst[k] = T[d][pc + k];  // scalar: start may be unaligned
}

// ---------------- flash attention: K dbuf + V single LDS (48KB), 8 waves, 1024 blocks ----------------
// grid 1024 = 8 bh (XCD-pinned, id&7) x 8 chunks of 256 keys x 16 q-tiles -> 3 blocks/CU usable
// (R18's 48KB LDS headroom was grid-limited at 512 blocks; this supplies the blocks).
// Per-wave work unchanged (16 q-rows); per-tile costs unchanged; total tile-visits unchanged.
__global__ __launch_bounds__(512) void attn(const u16* __restrict__ Qn,
        const u16* __restrict__ Kc, const u16* __restrict__ Vtc,
        const int* __restrict__ startp, const int* __restrict__ ctxp,
        u16* __restrict__ op, float* __restrict__ mp, float* __restrict__ lp) {
    __shared__ __align__(16) char KsB[2][16384];   // [buf][64 rows x 256B]
    __shared__ __align__(16) char VsB[16384];      // single: 128 rows x 128B
    const int tid = threadIdx.x, lane = tid & 63, w = tid >> 6;
    const int l15 = lane & 15, g = lane >> 4;
    const bool ghi = (g >= 2);
    const int id = blockIdx.x;
    const int bh = id & 7;                  // XCD-pinned
    const int rest = id >> 3;               // [0,128)
    const int c = rest & 7;                 // chunk 0..7
    const int q0 = (rest >> 3) * 32;        // q-tile 0..15
    const int b = bh >> 2, hkv = bh & 3;
    const int hd = w & 3, qh = w >> 2;
    const int hq = hkv * 4 + hd;
    const int start = startp[0];
    const int ctx = ctxp[b];

    int lim_blk = start + q0 + 32;
    if (lim_blk > ctx) lim_blk = ctx;
    const int pbeg = c * CHUNKP;
    int pend = pbeg + CHUNKP;
    if (pend > lim_blk) pend = lim_blk;
    if (pbeg >= pend) return;               // block-uniform (before any barrier)

    const int qrow0 = q0 + qh * 16;
    const long rowbase = (long)(b * 16 + hq) * 512 + qrow0;

    bf16x8 qb[4];
    {
        const u16* qp = Qn + (rowbase + l15) * 128 + g * 8;
#pragma unroll
        for (int kf = 0; kf < 4; ++kf)
            qb[kf] = *(const bf16x8*)(qp + kf * 32);
    }

    const char* kb8 = (const char*)(Kc + (long)bh * (MAXP_ * 128));
    const char* vb8 = (const char*)(Vtc + (long)bh * (128 * MAXP_));

    const int wbase = (tid & ~63) * 16;
    auto STAGE_K = [&](int buf, int p0_) {
#pragma unroll
        for (int r = 0; r < 2; ++r) {
            int o_ = r * 8192 + tid * 16;
            int row = o_ >> 8;
            int colb = (o_ & 255) ^ ((row & 7) << 4);
            GLOAD16(kb8 + (long)(p0_ + row) * 256 + colb, &KsB[buf][r * 8192 + wbase]);
        }
    };
    auto STAGE_V = [&](int p0_) {
#pragma unroll
        for (int r = 0; r < 2; ++r) {
            int o_ = r * 8192 + tid * 16;
            int row = o_ >> 7;
            int colb = (o_ & 127) ^ ((row & 7) << 4);
            GLOAD16(vb8 + (long)row * (MAXP_ * 2) + (long)p0_ * 2 + colb, &VsB[r * 8192 + wbase]);
        }
    };

    f32x4 o[8] = {};
    float m_run = -1e30f, l_run = 0.f;
    int limq = start + qrow0 + l15 + 1;
    if (limq > ctx) limq = ctx;
    if (limq > pend) limq = pend;
    const int addrA = (l15 + ((g & 1) << 5)) << 2;
    const int addrB = addrA + 64;
    const float scale = 0.08838834764831845f;
    const int swz = (l15 & 7) << 4;

    const int t0 = pbeg >> 6, t1 = (pend + 63) >> 6;
    STAGE_K(0, t0 * 64);
    asm volatile("s_waitcnt vmcnt(0)" ::: "memory");
    __builtin_amdgcn_s_barrier();
    int cur = 0;
    for (int t = t0; t < t1; ++t) {
        const int p0 = t * 64;
        STAGE_V(p0);                                 // V(t), oldest in flight
        const bool pf = (t + 1 < t1);
        if (pf) STAGE_K(cur ^ 1, p0 + 64);           // K(t+1), newest in flight
        // QK^T swapped: sacc[kt] = C[key=p0+kt*16+g*4+r][q=qrow0+l15]
        f32x4 sacc[4] = {};
#pragma unroll
        for (int kt = 0; kt < 4; ++kt) {
            const char* krow = &KsB[cur][(kt * 16 + l15) * 256];
#pragma unroll
            for (int kf = 0; kf < 4; ++kf) {
                bf16x8 ka = *(const bf16x8*)(krow + ((kf * 64 + g * 16) ^ swz));
                sacc[kt] = __builtin_amdgcn_mfma_f32_16x16x32_bf16(ka, qb[kf], sacc[kt], 0, 0, 0);
            }
        }
        // mask + online softmax with defer-max; stats per q=l15 (replicated over g)
        float mx = -1e30f;
#pragma unroll
        for (int kt = 0; kt < 4; ++kt)
#pragma unroll
            for (int r = 0; r < 4; ++r) {
                int key = p0 + kt * 16 + g * 4 + r;
                float x = (key < limq) ? sacc[kt][r] * scale : -1e30f;
                sacc[kt][r] = x;
                mx = fmaxf(mx, x);
            }
        mx = fmaxf(mx, __shfl_xor(mx, 16, 64));
        mx = fmaxf(mx, __shfl_xor(mx, 32, 64));
        if (!__all(mx <= m_run + 8.f)) {
            float mnew = fmaxf(m_run, mx);
            float alpha = __expf(m_run - mnew);
            m_run = mnew;
            l_run *= alpha;
            f32x4 av;
#pragma unroll
            for (int r = 0; r < 4; ++r) av[r] = __shfl(alpha, g * 4 + r, 64);
#pragma unroll
            for (int df = 0; df < 8; ++df) {
                o[df][0] *= av[0]; o[df][1] *= av[1];
                o[df][2] *= av[2]; o[df][3] *= av[3];
            }
        }
        const float mb = m_run;
        float rs = 0.f;
        u32 w0[4], w1[4];
#pragma unroll
        for (int kt = 0; kt < 4; ++kt) {
#pragma unroll
            for (int r = 0; r < 4; ++r) {
                float p = __expf(sacc[kt][r] - mb);
                sacc[kt][r] = p;
                rs += p;
            }
            w0[kt] = packbf(sacc[kt][0], sacc[kt][1]);
            w1[kt] = packbf(sacc[kt][2], sacc[kt][3]);
        }
        rs += __shfl_xor(rs, 16, 64);
        rs += __shfl_xor(rs, 32, 64);
        l_run += rs;
        // V(t) done (2 newest = K(t+1) may remain); then make visible to all waves
        if (pf) { asm volatile("s_waitcnt vmcnt(2)" ::: "memory"); }
        else    { asm volatile("s_waitcnt vmcnt(0)" ::: "memory"); }
        __builtin_amdgcn_s_barrier();
        // PV in two K=32 steps; P A-frag via bpermute; V from LDS (swizzled read)
#pragma unroll
        for (int ks = 0; ks < 2; ++ks) {
            const int sL = 2 * ks, sH = 2 * ks + 1;
            u32 d0 = ghi ? bperm(addrA, w0[sH]) : bperm(addrA, w0[sL]);
            u32 d1 = ghi ? bperm(addrA, w1[sH]) : bperm(addrA, w1[sL]);
            u32 d2 = ghi ? bperm(addrB, w0[sH]) : bperm(addrB, w0[sL]);
            u32 d3 = ghi ? bperm(addrB, w1[sH]) : bperm(addrB, w1[sL]);
            union { u32 d[4]; bf16x8 v; } pu;
            pu.d[0] = d0; pu.d[1] = d1; pu.d[2] = d2; pu.d[3] = d3;
            bf16x8 pa = pu.v;
#pragma unroll
            for (int df = 0; df < 8; ++df) {
                const char* vrow = &VsB[(df * 16 + l15) * 128];
                bf16x8 vb = *(const bf16x8*)(vrow + ((ks * 64 + g * 16) ^ swz));
                o[df] = __builtin_amdgcn_mfma_f32_16x16x32_bf16(pa, vb, o[df], 0, 0, 0);
            }
        }
        // K(t+1) complete + all waves done (V buffer free, K[cur^1] visible)
        asm volatile("s_waitcnt vmcnt(0)" ::: "memory");
        __builtin_amdgcn_s_barrier();
        cur ^= 1;
    }
    {
        float invl = l_run > 0.f ? 1.0f / l_run : 0.f;
        f32x4 iv;
#pragma unroll
        for (int r = 0; r < 4; ++r) iv[r] = __shfl(invl, g * 4 + r, 64);
        u16* dst = op + ((long)c * TOTROWS + rowbase + g * 4) * 128 + l15;
#pragma unroll
        for (int r = 0; r < 4; ++r)
#pragma unroll
            for (int df = 0; df < 8; ++df)
                dst[(long)r * 128 + df * 16] = f2bf(o[df][r] * iv[r]);
        if (g == 0) {
            mp[(long)c * TOTROWS + rowbase + l15] = m_run;
            lp[(long)c * TOTROWS + rowbase + l15] = l_run;
        }
    }
}

// ---------------- combine split-KV partials (8 chunks) -> Af bf16 [b*512+s][2048] ----------------
__global__ __launch_bounds__(256) void combine(const u16* __restrict__ op,
        const float* __restrict__ mp, const float* __restrict__ lp,
        const int* __restrict__ startp, const int* __restrict__ ctxp,
        u16* __restrict__ Af) {
    const int w = threadIdx.x >> 6, lane = threadIdx.x & 63;
    const long row = (long)blockIdx.x * 4 + w;
    const int b = (int)(row >> 13), hq = ((int)row >> 9) & 15, s = (int)row & 511;
    const int start = startp[0];
    int lim = start + s + 1;
    int cx = ctxp[b];
    if (lim > cx) lim = cx;
    float mc[NCALLOC], lc[NCALLOC];
    bool has[NCALLOC];
    float M = -1e30f;
#pragma unroll
    for (int c = 0; c < NCALLOC; ++c) {
        has[c] = (c * CHUNKP < lim);
        if (has[c]) {
            mc[c] = mp[(long)c * TOTROWS + row];
            lc[c] = lp[(long)c * TOTROWS + row];
            if (lc[c] > 0.f && mc[c] > M) M = mc[c];
        }
    }
    const int d0 = lane * 2;
    float Wt = 0.f, a0 = 0.f, a1 = 0.f;
#pragma unroll
    for (int c = 0; c < NCALLOC; ++c) {
        if (has[c] && lc[c] > 0.f) {
            float wg = lc[c] * __expf(mc[c] - M);
            Wt += wg;
            u32 pr = *(const u32*)&op[((long)c * TOTROWS + row) * 128 + d0];
            a0 += wg * bf2f((u16)(pr & 0xFFFF));
            a1 += wg * bf2f((u16)(pr >> 16));
        }
    }
    float inv = 1.0f / Wt;
    u32 pk = (u32)f2bf(a0 * inv) | ((u32)f2bf(a1 * inv) << 16);
    *(u32*)&Af[((long)(b * 512 + s) * 2048) + hq * 128 + d0] = pk;
}

extern "C" void kernel_launch(void* const* d_in, const int* in_sizes, int n_in,
                              void* d_out, int out_size, void* d_ws, size_t ws_size,
                              hipStream_t stream) {
    const float* hidden = (const float*)d_in[0];
    const float* past   = (const float*)d_in[1];
    const float* rope   = (const float*)d_in[2];
    const float* Wq     = (const float*)d_in[3];
    const float* Wk     = (const float*)d_in[4];
    const float* Wv     = (const float*)d_in[5];
    const float* Wo     = (const float*)d_in[6];
    const float* qw     = (const float*)d_in[7];
    const float* kw     = (const float*)d_in[8];
    const int*   ctx    = (const int*)d_in[9];
    const int*   start  = (const int*)d_in[10];

    float* out = (float*)d_out;
    float* present = out + 2097152;
    u16* Kc = (u16*)d_out;   // parked in attn-output region of d_out

    // ws layout (ws_size = 256 MiB per harness poison-fill; budget 63 MiB):
    //   early overlay: hb[0,4M) | Wqkvt[4M,16M) | QKVf[16M,28M)    (all dead before attn)
    //   op   [0,32M)      attn partials, 8 chunks                  (written by attn only)
    //   mp   [32M,32.5M)  lp [32.5M,33M)
    //   Qn   [33.5M,37.5M)  (written by normrope_v; > QKVf end 28M ✓)
    //   Vtc  [37.75M,45.75M)
    //   Wot  [46M,54M)
    //   Af   [54M,58M)
    char* wsb = (char*)d_ws;
    u16*   hb    = (u16*)(wsb + 0);
    u16*   Wqkvt = (u16*)(wsb + 4194304);
    float* QKVf  = (float*)(wsb + 16777216);
    u16*   op    = (u16*)(wsb + 0);
    float* mp    = (float*)(wsb + 33554432);
    float* lp    = (float*)(wsb + 34078720);
    u16*   Qn    = (u16*)(wsb + 35127296);
    u16*   Vtc   = (u16*)(wsb + 39583744);
    u16*   Wot   = (u16*)(wsb + 48234496);
    u16*   Af    = (u16*)(wsb + 56623104);

    // past -> present: dedicated d2d copy (blit path); must precede normrope_v.
    hipMemcpyAsync(present, past, 33554432ull, hipMemcpyDeviceToDevice, stream);

    prep<<<dim3(4608), dim3(256), 0, stream>>>(hidden, Wq, Wk, Wv, Wo, past,
            hb, Wqkvt, Wot, Kc, Vtc, start, ctx);                                       // 1
    gemm64<<<dim3(768), dim3(256), 0, stream>>>(hb, Wqkvt, QKVf, 1024, 3072, 2048);     // 2
    normrope_v<<<dim3(6208), dim3(256), 0, stream>>>(QKVf, rope, qw, kw, start, present, Qn, Kc, Vtc); // 3
    attn<<<dim3(1024), dim3(512), 0, stream>>>(Qn, Kc, Vtc, start, ctx, op, mp, lp);    // 4
    combine<<<dim3(4096), dim3(256), 0, stream>>>(op, mp, lp, start, ctx, Af);          // 5
    gemm64<<<dim3(512), dim3(256), 0, stream>>>(Af, Wot, out, 1024, 2048, 2048);        // 6
}

// Round 20
// 118.426 us; speedup vs baseline: 1.0801x; 1.0801x over previous
//
#include <hip/hip_runtime.h>

typedef unsigned short u16;
typedef unsigned int u32;
typedef __attribute__((ext_vector_type(4))) float f32x4;
typedef __attribute__((ext_vector_type(8))) __bf16 bf16x8;
typedef __attribute__((ext_vector_type(8))) unsigned short u16x8;

#define MAXP_ 4096
#define TOTROWS 16384   // B*HQ*S = 2*16*512
#define NCHUNK 4
#define NCALLOC 4
#define CHUNKP 512

__device__ __forceinline__ u16 f2bf(float f) {
    union { float f; u32 u; } x; x.f = f;
    u32 r = x.u + 0x7FFFu + ((x.u >> 16) & 1u);
    return (u16)(r >> 16);
}
__device__ __forceinline__ float bf2f(u16 u) {
    union { u32 u; float f; } x; x.u = ((u32)u) << 16; return x.f;
}
// RNE bf16 pair pack
__device__ __forceinline__ u32 packbf(float lo, float hi) {
    return (u32)f2bf(lo) | ((u32)f2bf(hi) << 16);
}
__device__ __forceinline__ u32 bperm(int addr, u32 src) {
    return (u32)__builtin_amdgcn_ds_bpermute(addr, (int)src);
}

#define GLOAD16(g, l) __builtin_amdgcn_global_load_lds( \
    (const __attribute__((address_space(1))) void*)(g), \
    (__attribute__((address_space(3))) void*)(l), 16, 0, 0)

// ---------------- mega-prep: cvt + Wq/Wk/Wv/Wo transpose + K/V bf16 caches ----------------
// grid audit (R14 lesson): [0,1024) cvt | [1024,2048) Wq | [2048,2304) Wk | [2304,2560) Wv |
//                          [2560,3584) K/V caches (16 bkh x 64 p-tiles) | [3584,4608) Wo. grid=4608.
__global__ __launch_bounds__(256) void prep(const float* __restrict__ hidden,
        const float* __restrict__ Wq, const float* __restrict__ Wk, const float* __restrict__ Wv,
        const float* __restrict__ Wo, const float* __restrict__ past,
        u16* __restrict__ hb, u16* __restrict__ Wqkvt, u16* __restrict__ Wot,
        u16* __restrict__ Kc, u16* __restrict__ Vtc,
        const int* __restrict__ startp, const int* __restrict__ ctxp) {
    __shared__ __align__(16) u16 T[128][72];
    const int bid = blockIdx.x;
    const int t = threadIdx.x;
    if (bid < 1024) {   // cvt: 262144 groups of 8
        int i = bid * 256 + t;
        const float* s = hidden + (long)i * 8;
        f32x4 a = *(const f32x4*)s;
        f32x4 b = *(const f32x4*)(s + 4);
        u16x8 o;
#pragma unroll
        for (int j = 0; j < 4; ++j) { o[j] = f2bf(a[j]); o[4 + j] = f2bf(b[j]); }
        *(u16x8*)&hb[(long)i * 8] = o;
        return;
    }
    if (bid >= 2560 && bid < 3584) {   // bf16 K / V^T caches from past
        const int b2 = bid - 2560;
        const int bkh = b2 >> 6;            // (b*2+kv)*4+h
        const int p0 = (b2 & 63) * 64;
        const int b = bkh >> 3, kv = (bkh >> 2) & 1, h = bkh & 3;
        int klim = startp[0] + 512;
        int cx = ctxp[b];
        if (klim > cx) klim = cx;
        if (p0 >= klim) return;             // block-uniform
        const int p = t >> 2, d0 = (t & 3) * 32;
        const float* src = past + ((long)bkh * MAXP_ + p0 + p) * 128 + d0;
        f32x4 v[8];
#pragma unroll
        for (int j = 0; j < 8; ++j) v[j] = *(const f32x4*)(src + j * 4);
        if (kv == 0) {
            u16* kd = Kc + ((long)(b * 4 + h) * MAXP_ + p0 + p) * 128 + d0;
#pragma unroll
            for (int j2 = 0; j2 < 4; ++j2) {
                u16x8 o;
#pragma unroll
                for (int e = 0; e < 4; ++e) { o[e] = f2bf(v[j2 * 2][e]); o[4 + e] = f2bf(v[j2 * 2 + 1][e]); }
                *(u16x8*)&kd[j2 * 8] = o;
            }
        } else {
#pragma unroll
            for (int j = 0; j < 8; ++j)
#pragma unroll
                for (int e = 0; e < 4; ++e)
                    T[d0 + j * 4 + e][p] = f2bf(v[j][e]);
            __syncthreads();
            int d = t >> 1, pc = (t & 1) * 32;
            u16* vd = Vtc + ((long)(b * 4 + h) * 128 + d) * MAXP_ + p0 + pc;
#pragma unroll
            for (int j = 0; j < 4; ++j)
                *(u16x8*)&vd[j * 8] = *(const u16x8*)&T[d][pc + j * 8];
        }
        return;
    }
    // weight transpose branches (use rows [0,64) of T)
    const float* W; u16* Wdst; int N_w, n_off, n0, k0;
    if (bid < 2048)      { int b2 = bid - 1024; W = Wq; Wdst = Wqkvt; N_w = 2048; n_off = 0;    n0 = (b2 & 31) * 64; k0 = (b2 >> 5) * 64; }
    else if (bid < 2304) { int b2 = bid - 2048; W = Wk; Wdst = Wqkvt; N_w = 512;  n_off = 2048; n0 = (b2 & 7) * 64;  k0 = (b2 >> 3) * 64; }
    else if (bid < 2560) { int b2 = bid - 2304; W = Wv; Wdst = Wqkvt; N_w = 512;  n_off = 2560; n0 = (b2 & 7) * 64;  k0 = (b2 >> 3) * 64; }
    else                 { int b2 = bid - 3584; W = Wo; Wdst = Wot;   N_w = 2048; n_off = 0;    n0 = (b2 & 31) * 64; k0 = (b2 >> 5) * 64; }
    {
        int r = t >> 2, c4 = (t & 3) * 16;
        const float* src = W + (long)(k0 + r) * N_w + n0 + c4;
        f32x4 a0 = *(const f32x4*)src, a1 = *(const f32x4*)(src + 4);
        f32x4 a2 = *(const f32x4*)(src + 8), a3 = *(const f32x4*)(src + 12);
        u16x8 p0, p1;
#pragma unroll
        for (int j = 0; j < 4; ++j) {
            p0[j] = f2bf(a0[j]); p0[4 + j] = f2bf(a1[j]);
            p1[j] = f2bf(a2[j]); p1[4 + j] = f2bf(a3[j]);
        }
        *(u16x8*)&T[r][c4] = p0;
        *(u16x8*)&T[r][c4 + 8] = p1;
    }
    __syncthreads();
    {
        int n = t >> 2, k4 = (t & 3) * 16;
        u16x8 q0, q1;
#pragma unroll
        for (int j = 0; j < 8; ++j) { q0[j] = T[k4 + j][n]; q1[j] = T[k4 + 8 + j][n]; }
        u16* dst = Wdst + (long)(n_off + n0 + n) * 2048 + k0 + k4;
        *(u16x8*)dst = q0;
        *(u16x8*)(dst + 8) = q1;
    }
}

// ---------------- bf16 GEMM, A[M][K] @ Bt[N][K]^T -> C[M][N] f32 ----------------
// 64x64 tile, BK=64, dbuf gload_lds + counted vmcnt. 1D grid with XCD-pinned n-ranges (T1).
__global__ __launch_bounds__(256) void gemm64(const u16* __restrict__ A, const u16* __restrict__ Bt,
                                              float* __restrict__ C, int M, int N, int K) {
    __shared__ __align__(16) u16 As0[4096], Bs0[4096], As1[4096], Bs1[4096];
    const int tid = threadIdx.x, lane = tid & 63, w = tid >> 6;
    const int wm = w >> 1, wn = w & 1;
    const int l15 = lane & 15, g = lane >> 4;
    const int ntile = N >> 6, npx = ntile >> 3;
    const int xcd = blockIdx.x & 7, j_ = blockIdx.x >> 3;
    const int m0 = (j_ / npx) * 64, n0 = (xcd * npx + j_ % npx) * 64;
    f32x4 acc[2][2] = {};

    const int lrow = lane >> 3;
    const int sch = (lane & 7) ^ lrow;
    const int c0 = w, c1 = w + 4;
    const u16* ga0 = A + (long)(m0 + c0 * 8 + lrow) * K + sch * 8;
    const u16* ga1 = A + (long)(m0 + c1 * 8 + lrow) * K + sch * 8;
    const u16* gb0 = Bt + (long)(n0 + c0 * 8 + lrow) * K + sch * 8;
    const u16* gb1 = Bt + (long)(n0 + c1 * 8 + lrow) * K + sch * 8;
    const int ra = wm * 32, rb = wn * 32;
    const int h7 = l15 & 7;

#define STAGE_T(koff, AS_, BS_) do { \
        GLOAD16(ga0 + (koff), &AS_[c0 * 512]); \
        GLOAD16(ga1 + (koff), &AS_[c1 * 512]); \
        GLOAD16(gb0 + (koff), &BS_[c0 * 512]); \
        GLOAD16(gb1 + (koff), &BS_[c1 * 512]); \
    } while (0)

    auto compute = [&](const u16* as_, const u16* bs_) {
        bf16x8 af[2][2], bfr[2][2];
#pragma unroll
        for (int i = 0; i < 2; ++i) {
            int rr = ra + i * 16 + l15;
#pragma unroll
            for (int kk = 0; kk < 2; ++kk)
                af[i][kk] = *(const bf16x8*)&as_[rr * 64 + (((kk * 4 + g) ^ h7) * 8)];
        }
#pragma unroll
        for (int j2 = 0; j2 < 2; ++j2) {
            int rr = rb + j2 * 16 + l15;
#pragma unroll
            for (int kk = 0; kk < 2; ++kk)
                bfr[j2][kk] = *(const bf16x8*)&bs_[rr * 64 + (((kk * 4 + g) ^ h7) * 8)];
        }
#pragma unroll
        for (int i = 0; i < 2; ++i)
#pragma unroll
            for (int j2 = 0; j2 < 2; ++j2) {
                acc[i][j2] = __builtin_amdgcn_mfma_f32_16x16x32_bf16(af[i][0], bfr[j2][0], acc[i][j2], 0, 0, 0);
                acc[i][j2] = __builtin_amdgcn_mfma_f32_16x16x32_bf16(af[i][1], bfr[j2][1], acc[i][j2], 0, 0, 0);
            }
    };

    STAGE_T(0, As0, Bs0);
    for (int k0 = 0; k0 < K; k0 += 128) {
        STAGE_T(k0 + 64, As1, Bs1);
        asm volatile("s_waitcnt vmcnt(4)" ::: "memory");
        __builtin_amdgcn_s_barrier();
        __builtin_amdgcn_sched_barrier(0);
        compute(As0, Bs0);
        __builtin_amdgcn_s_barrier();
        if (k0 + 128 < K) {
            STAGE_T(k0 + 128, As0, Bs0);
            asm volatile("s_waitcnt vmcnt(4)" ::: "memory");
        } else {
            asm volatile("s_waitcnt vmcnt(0)" ::: "memory");
        }
        __builtin_amdgcn_s_barrier();
        __builtin_amdgcn_sched_barrier(0);
        compute(As1, Bs1);
        __builtin_amdgcn_s_barrier();
    }
#undef STAGE_T

#pragma unroll
    for (int i = 0; i < 2; ++i)
#pragma unroll
        for (int j2 = 0; j2 < 2; ++j2)
#pragma unroll
            for (int r = 0; r < 4; ++r)
                C[(long)(m0 + ra + i * 16 + g * 4 + r) * N + n0 + rb + j2 * 16 + l15] = acc[i][j2][r];
}

// ---------------- fused RMS norm + RoPE + cache scatter + new-V transpose ----------------
__global__ __launch_bounds__(256) void normrope_v(const float* __restrict__ QKVf,
        const float* __restrict__ rope,
        const float* __restrict__ qw, const float* __restrict__ kw,
        const int* __restrict__ startp, float* __restrict__ present,
        u16* __restrict__ Qn, u16* __restrict__ Kc, u16* __restrict__ Vtc) {
    const int bid = blockIdx.x;
    const int start = startp[0];
    if (bid < 6144) {
        const int wid = bid * 4 + (threadIdx.x >> 6);
        const int lane = threadIdx.x & 63;
        if (wid < 16384) { // Q: 1024 rows x 16 heads
            int row = wid >> 4, h = wid & 15;
            int b = row >> 9, s = row & 511;
            const float* src = QKVf + (long)row * 3072 + h * 128;
            float x1 = src[lane], x2 = src[64 + lane];
            float v = x1 * x1 + x2 * x2;
#pragma unroll
            for (int off = 32; off; off >>= 1) v += __shfl_xor(v, off, 64);
            float sc = rsqrtf(v * (1.0f / 128.0f) + 1e-6f);
            float y1 = x1 * sc * qw[lane], y2 = x2 * sc * qw[64 + lane];
            float c = rope[(long)row * 128 + lane], sn = rope[(long)row * 128 + 64 + lane];
            u16* dst = Qn + (((long)(b * 16 + h) * 512 + s) * 128);
            dst[lane] = f2bf(y1 * c - y2 * sn);
            dst[64 + lane] = f2bf(y2 * c + y1 * sn);
        } else if (wid < 20480) { // K: 1024 rows x 4 heads
            int j = wid - 16384;
            int row = j >> 2, h = j & 3;
            int b = row >> 9, s = row & 511;
            const float* src = QKVf + (long)row * 3072 + 2048 + h * 128;
            float x1 = src[lane], x2 = src[64 + lane];
            float v = x1 * x1 + x2 * x2;
#pragma unroll
            for (int off = 32; off; off >>= 1) v += __shfl_xor(v, off, 64);
            float sc = rsqrtf(v * (1.0f / 128.0f) + 1e-6f);
            float y1 = x1 * sc * kw[lane], y2 = x2 * sc * kw[64 + lane];
            float c = rope[(long)row * 128 + lane], sn = rope[(long)row * 128 + 64 + lane];
            float k1 = y1 * c - y2 * sn, k2 = y2 * c + y1 * sn;
            float* dst = present + (((long)(b * 2 + 0) * 4 + h) * MAXP_ + (start + s)) * 128;
            dst[lane] = k1; dst[64 + lane] = k2;
            u16* kc = Kc + (((long)(b * 4 + h)) * MAXP_ + start + s) * 128;
            kc[lane] = f2bf(k1); kc[64 + lane] = f2bf(k2);
        } else if (wid < 24576) { // V: present copy only
            int j = wid - 20480;
            int row = j >> 2, h = j & 3;
            int b = row >> 9, s = row & 511;
            const float* src = QKVf + (long)row * 3072 + 2560 + h * 128;
            float* dst = present + (((long)(b * 2 + 1) * 4 + h) * MAXP_ + (start + s)) * 128;
            dst[lane] = src[lane];
            dst[64 + lane] = src[64 + lane];
        }
        return;
    }
    // vtrans: new V -> Vtc bf16 [d][p]
    __shared__ __align__(16) u16 T[128][72];
    const int t = threadIdx.x;
    const int b2 = bid - 6144;
    const int s0 = (b2 & 7) * 64;
    const int bh = b2 >> 3, b = bh >> 2, h = bh & 3;
    const int sr = t >> 2, d0 = (t & 3) * 32;
    const float* src = QKVf + (long)(b * 512 + s0 + sr) * 3072 + 2560 + h * 128 + d0;
#pragma unroll
    for (int j = 0; j < 8; ++j) {
        f32x4 v = *(const f32x4*)(src + j * 4);
#pragma unroll
        for (int e = 0; e < 4; ++e) T[d0 + j * 4 + e][sr] = f2bf(v[e]);
    }
    __syncthreads();
    const int d = t >> 1, pc = (t & 1) * 32;
    u16* dst = Vtc + ((long)(b * 4 + h) * 128 + d) * MAXP_ + start + s0 + pc;
#pragma unroll
    for (int k = 0; k < 32; ++k) dst[k] = T[d][pc + k];  // scalar: start may be unaligned
}

// ---------------- flash attention: K dbuf + V single LDS (48KB), 8 waves, 512 blocks (R18) ----------------
// + T5 s_setprio around the MFMA clusters (re-test in the LDS-staged regime; rule #23).
__global__ __launch_bounds__(512) void attn(const u16* __restrict__ Qn,
        const u16* __restrict__ Kc, const u16* __restrict__ Vtc,
        const int* __restrict__ startp, const int* __restrict__ ctxp,
        u16* __restrict__ op, float* __restrict__ mp, float* __restrict__ lp) {
    __shared__ __align__(16) char KsB[2][16384];   // [buf][64 rows x 256B]
    __shared__ __align__(16) char VsB[16384];      // single: 128 rows x 128B
    const int tid = threadIdx.x, lane = tid & 63, w = tid >> 6;
    const int l15 = lane & 15, g = lane >> 4;
    const bool ghi = (g >= 2);
    const int id = blockIdx.x;
    const int bh = id & 7;                  // XCD-pinned
    const int rest = id >> 3;
    const int c = rest >> 4;                // chunk 0..3
    const int q0 = (rest & 15) * 32;        // q-tile origin
    const int b = bh >> 2, hkv = bh & 3;
    const int hd = w & 3, qh = w >> 2;
    const int hq = hkv * 4 + hd;
    const int start = startp[0];
    const int ctx = ctxp[b];

    int lim_blk = start + q0 + 32;
    if (lim_blk > ctx) lim_blk = ctx;
    const int pbeg = c * CHUNKP;
    int pend = pbeg + CHUNKP;
    if (pend > lim_blk) pend = lim_blk;
    if (pbeg >= pend) return;               // block-uniform (before any barrier)

    const int qrow0 = q0 + qh * 16;
    const long rowbase = (long)(b * 16 + hq) * 512 + qrow0;

    bf16x8 qb[4];
    {
        const u16* qp = Qn + (rowbase + l15) * 128 + g * 8;
#pragma unroll
        for (int kf = 0; kf < 4; ++kf)
            qb[kf] = *(const bf16x8*)(qp + kf * 32);
    }

    const char* kb8 = (const char*)(Kc + (long)bh * (MAXP_ * 128));
    const char* vb8 = (const char*)(Vtc + (long)bh * (128 * MAXP_));

    const int wbase = (tid & ~63) * 16;
    auto STAGE_K = [&](int buf, int p0_) {
#pragma unroll
        for (int r = 0; r < 2; ++r) {
            int o_ = r * 8192 + tid * 16;
            int row = o_ >> 8;
            int colb = (o_ & 255) ^ ((row & 7) << 4);
            GLOAD16(kb8 + (long)(p0_ + row) * 256 + colb, &KsB[buf][r * 8192 + wbase]);
        }
    };
    auto STAGE_V = [&](int p0_) {
#pragma unroll
        for (int r = 0; r < 2; ++r) {
            int o_ = r * 8192 + tid * 16;
            int row = o_ >> 7;
            int colb = (o_ & 127) ^ ((row & 7) << 4);
            GLOAD16(vb8 + (long)row * (MAXP_ * 2) + (long)p0_ * 2 + colb, &VsB[r * 8192 + wbase]);
        }
    };

    f32x4 o[8] = {};
    float m_run = -1e30f, l_run = 0.f;
    int limq = start + qrow0 + l15 + 1;
    if (limq > ctx) limq = ctx;
    if (limq > pend) limq = pend;
    const int addrA = (l15 + ((g & 1) << 5)) << 2;
    const int addrB = addrA + 64;
    const float scale = 0.08838834764831845f;
    const int swz = (l15 & 7) << 4;

    const int t0 = pbeg >> 6, t1 = (pend + 63) >> 6;
    STAGE_K(0, t0 * 64);
    asm volatile("s_waitcnt vmcnt(0)" ::: "memory");
    __builtin_amdgcn_s_barrier();
    int cur = 0;
    for (int t = t0; t < t1; ++t) {
        const int p0 = t * 64;
        STAGE_V(p0);                                 // V(t), oldest in flight
        const bool pf = (t + 1 < t1);
        if (pf) STAGE_K(cur ^ 1, p0 + 64);           // K(t+1), newest in flight
        // QK^T swapped: sacc[kt] = C[key=p0+kt*16+g*4+r][q=qrow0+l15]
        f32x4 sacc[4] = {};
        __builtin_amdgcn_s_setprio(1);
#pragma unroll
        for (int kt = 0; kt < 4; ++kt) {
            const char* krow = &KsB[cur][(kt * 16 + l15) * 256];
#pragma unroll
            for (int kf = 0; kf < 4; ++kf) {
                bf16x8 ka = *(const bf16x8*)(krow + ((kf * 64 + g * 16) ^ swz));
                sacc[kt] = __builtin_amdgcn_mfma_f32_16x16x32_bf16(ka, qb[kf], sacc[kt], 0, 0, 0);
            }
        }
        __builtin_amdgcn_s_setprio(0);
        // mask + online softmax with defer-max; stats per q=l15 (replicated over g)
        float mx = -1e30f;
#pragma unroll
        for (int kt = 0; kt < 4; ++kt)
#pragma unroll
            for (int r = 0; r < 4; ++r) {
                int key = p0 + kt * 16 + g * 4 + r;
                float x = (key < limq) ? sacc[kt][r] * scale : -1e30f;
                sacc[kt][r] = x;
                mx = fmaxf(mx, x);
            }
        mx = fmaxf(mx, __shfl_xor(mx, 16, 64));
        mx = fmaxf(mx, __shfl_xor(mx, 32, 64));
        if (!__all(mx <= m_run + 8.f)) {
            float mnew = fmaxf(m_run, mx);
            float alpha = __expf(m_run - mnew);
            m_run = mnew;
            l_run *= alpha;
            f32x4 av;
#pragma unroll
            for (int r = 0; r < 4; ++r) av[r] = __shfl(alpha, g * 4 + r, 64);
#pragma unroll
            for (int df = 0; df < 8; ++df) {
                o[df][0] *= av[0]; o[df][1] *= av[1];
                o[df][2] *= av[2]; o[df][3] *= av[3];
            }
        }
        const float mb = m_run;
        float rs = 0.f;
        u32 w0[4], w1[4];
#pragma unroll
        for (int kt = 0; kt < 4; ++kt) {
#pragma unroll
            for (int r = 0; r < 4; ++r) {
                float p = __expf(sacc[kt][r] - mb);
                sacc[kt][r] = p;
                rs += p;
            }
            w0[kt] = packbf(sacc[kt][0], sacc[kt][1]);
            w1[kt] = packbf(sacc[kt][2], sacc[kt][3]);
        }
        rs += __shfl_xor(rs, 16, 64);
        rs += __shfl_xor(rs, 32, 64);
        l_run += rs;
        // V(t) done (2 newest = K(t+1) may remain); then make visible to all waves
        if (pf) { asm volatile("s_waitcnt vmcnt(2)" ::: "memory"); }
        else    { asm volatile("s_waitcnt vmcnt(0)" ::: "memory"); }
        __builtin_amdgcn_s_barrier();
        // PV in two K=32 steps; P A-frag via bpermute; V from LDS (swizzled read)
#pragma unroll
        for (int ks = 0; ks < 2; ++ks) {
            const int sL = 2 * ks, sH = 2 * ks + 1;
            u32 d0 = ghi ? bperm(addrA, w0[sH]) : bperm(addrA, w0[sL]);
            u32 d1 = ghi ? bperm(addrA, w1[sH]) : bperm(addrA, w1[sL]);
            u32 d2 = ghi ? bperm(addrB, w0[sH]) : bperm(addrB, w0[sL]);
            u32 d3 = ghi ? bperm(addrB, w1[sH]) : bperm(addrB, w1[sL]);
            union { u32 d[4]; bf16x8 v; } pu;
            pu.d[0] = d0; pu.d[1] = d1; pu.d[2] = d2; pu.d[3] = d3;
            bf16x8 pa = pu.v;
            __builtin_amdgcn_s_setprio(1);
#pragma unroll
            for (int df = 0; df < 8; ++df) {
                const char* vrow = &VsB[(df * 16 + l15) * 128];
                bf16x8 vb = *(const bf16x8*)(vrow + ((ks * 64 + g * 16) ^ swz));
                o[df] = __builtin_amdgcn_mfma_f32_16x16x32_bf16(pa, vb, o[df], 0, 0, 0);
            }
            __builtin_amdgcn_s_setprio(0);
        }
        // K(t+1) complete + all waves done (V buffer free, K[cur^1] visible)
        asm volatile("s_waitcnt vmcnt(0)" ::: "memory");
        __builtin_amdgcn_s_barrier();
        cur ^= 1;
    }
    {
        float invl = l_run > 0.f ? 1.0f / l_run : 0.f;
        f32x4 iv;
#pragma unroll
        for (int r = 0; r < 4; ++r) iv[r] = __shfl(invl, g * 4 + r, 64);
        u16* dst = op + ((long)c * TOTROWS + rowbase + g * 4) * 128 + l15;
#pragma unroll
        for (int r = 0; r < 4; ++r)
#pragma unroll
            for (int df = 0; df < 8; ++df)
                dst[(long)r * 128 + df * 16] = f2bf(o[df][r] * iv[r]);
        if (g == 0) {
            mp[(long)c * TOTROWS + rowbase + l15] = m_run;
            lp[(long)c * TOTROWS + rowbase + l15] = l_run;
        }
    }
}

// ---------------- combine split-KV partials -> Af bf16 [b*512+s][2048] ----------------
__global__ __launch_bounds__(256) void combine(const u16* __restrict__ op,
        const float* __restrict__ mp, const float* __restrict__ lp,
        const int* __restrict__ startp, const int* __restrict__ ctxp,
        u16* __restrict__ Af) {
    const int w = threadIdx.x >> 6, lane = threadIdx.x & 63;
    const long row = (long)blockIdx.x * 4 + w;
    const int b = (int)(row >> 13), hq = ((int)row >> 9) & 15, s = (int)row & 511;
    const int start = startp[0];
    int lim = start + s + 1;
    int cx = ctxp[b];
    if (lim > cx) lim = cx;
    float mc[NCALLOC], lc[NCALLOC];
    bool has[NCALLOC];
    float M = -1e30f;
#pragma unroll
    for (int c = 0; c < NCALLOC; ++c) {
        has[c] = (c * CHUNKP < lim);
        if (has[c]) {
            mc[c] = mp[(long)c * TOTROWS + row];
            lc[c] = lp[(long)c * TOTROWS + row];
            if (lc[c] > 0.f && mc[c] > M) M = mc[c];
        }
    }
    const int d0 = lane * 2;
    float Wt = 0.f, a0 = 0.f, a1 = 0.f;
#pragma unroll
    for (int c = 0; c < NCALLOC; ++c) {
        if (has[c] && lc[c] > 0.f) {
            float wg = lc[c] * __expf(mc[c] - M);
            Wt += wg;
            u32 pr = *(const u32*)&op[((long)c * TOTROWS + row) * 128 + d0];
            a0 += wg * bf2f((u16)(pr & 0xFFFF));
            a1 += wg * bf2f((u16)(pr >> 16));
        }
    }
    float inv = 1.0f / Wt;
    u32 pk = (u32)f2bf(a0 * inv) | ((u32)f2bf(a1 * inv) << 16);
    *(u32*)&Af[((long)(b * 512 + s) * 2048) + hq * 128 + d0] = pk;
}

extern "C" void kernel_launch(void* const* d_in, const int* in_sizes, int n_in,
                              void* d_out, int out_size, void* d_ws, size_t ws_size,
                              hipStream_t stream) {
    const float* hidden = (const float*)d_in[0];
    const float* past   = (const float*)d_in[1];
    const float* rope   = (const float*)d_in[2];
    const float* Wq     = (const float*)d_in[3];
    const float* Wk     = (const float*)d_in[4];
    const float* Wv     = (const float*)d_in[5];
    const float* Wo     = (const float*)d_in[6];
    const float* qw     = (const float*)d_in[7];
    const float* kw     = (const float*)d_in[8];
    const int*   ctx    = (const int*)d_in[9];
    const int*   start  = (const int*)d_in[10];

    float* out = (float*)d_out;
    float* present = out + 2097152;
    u16* Kc = (u16*)d_out;   // parked in attn-output region of d_out

    // ws layout (ws_size = 256 MiB per harness poison-fill; budget 58 MiB):
    //   early overlay: hb[0,4M) | Wqkvt[4M,16M) | QKVf[16M,28M)   (dead before attn)
    //   op [0,16M) (4 chunks) | mp[32M,32.5M) lp[32.5M,33M)
    //   Qn [33.5M,37.5M) | Vtc [37.75M,45.75M) | Wot [46M,54M) | Af [54M,58M)
    char* wsb = (char*)d_ws;
    u16*   hb    = (u16*)(wsb + 0);
    u16*   Wqkvt = (u16*)(wsb + 4194304);
    float* QKVf  = (float*)(wsb + 16777216);
    u16*   op    = (u16*)(wsb + 0);
    float* mp    = (float*)(wsb + 33554432);
    float* lp    = (float*)(wsb + 34078720);
    u16*   Qn    = (u16*)(wsb + 35127296);
    u16*   Vtc   = (u16*)(wsb + 39583744);
    u16*   Wot   = (u16*)(wsb + 48234496);
    u16*   Af    = (u16*)(wsb + 56623104);

    // past -> present: dedicated d2d copy (blit path); must precede normrope_v.
    hipMemcpyAsync(present, past, 33554432ull, hipMemcpyDeviceToDevice, stream);

    prep<<<dim3(4608), dim3(256), 0, stream>>>(hidden, Wq, Wk, Wv, Wo, past,
            hb, Wqkvt, Wot, Kc, Vtc, start, ctx);                                       // 1
    gemm64<<<dim3(768), dim3(256), 0, stream>>>(hb, Wqkvt, QKVf, 1024, 3072, 2048);     // 2
    normrope_v<<<dim3(6208), dim3(256), 0, stream>>>(QKVf, rope, qw, kw, start, present, Qn, Kc, Vtc); // 3
    attn<<<dim3(512), dim3(512), 0, stream>>>(Qn, Kc, Vtc, start, ctx, op, mp, lp);     // 4
    combine<<<dim3(4096), dim3(256), 0, stream>>>(op, mp, lp, start, ctx, Af);          // 5
    gemm64<<<dim3(512), dim3(256), 0, stream>>>(Af, Wot, out, 1024, 2048, 2048);        // 6
}